// Round 19
// baseline (645.883 us; speedup 1.0000x reference)
//
#include <hip/hip_runtime.h>
#include <cstdint>

#define HB 128    // hidden size
#define NB 64     // graphs per batch
#define NE 1048576
#define SLAB 16384  // per-graph edge slab (NE/NB), constant across layers
#define XP 132    // padded LDS row stride (floats)

typedef float v2f __attribute__((ext_vector_type(2)));

// ---- init edge arrays + layer-0 edge-count metadata ----
__global__ __launch_bounds__(256) void init_edges_k(const int* __restrict__ ei,
    int* __restrict__ row, int* __restrict__ col, int* __restrict__ gcnt0, int E) {
  int e = blockIdx.x * blockDim.x + threadIdx.x;
  if (e < E) { row[e] = ei[e]; col[e] = ei[E + e]; }
  if (blockIdx.x == 0 && threadIdx.x < NB) gcnt0[threadIdx.x] = SLAB;
}

// ---- fused layer-0 dense chain: out = relu((aggx@Wc1 + bc) @ Wf + bf) ----
__global__ __launch_bounds__(256) void conv_fc0_k(const float* __restrict__ aggx,
    const float* __restrict__ Wc1, const float* __restrict__ bc0,
    const float* __restrict__ Wf, const float* __restrict__ bf0,
    float* __restrict__ out, int N, float* __restrict__ stat) {
  __shared__ float lt[64][128];      // 32KB; red aliases front 8KB after final sync
  __shared__ float laggx[64][8];
  __shared__ float lwc1[7 * 128];
  float2 (*red)[128] = (float2(*)[128])lt;
  int tid = threadIdx.x;
  int tx = tid & 31, ty = tid >> 5;
  long rowbase = (long)blockIdx.x * 64;
  for (int i = tid; i < 7 * 32; i += 256)
    ((float4*)lwc1)[i] = ((const float4*)Wc1)[i];
  if (tid < 128) {
    int lr = tid >> 1, lq = (tid & 1) * 4;
    *(float4*)&laggx[lr][lq] = *(const float4*)(aggx + (rowbase + lr) * 8 + lq);
  }
  __syncthreads();
  float4 tacc[8];
  float4 bcv = ((const float4*)bc0)[tx];
  #pragma unroll
  for (int r = 0; r < 8; ++r) tacc[r] = bcv;
  #pragma unroll
  for (int k = 0; k < 7; ++k) {
    float4 wv = ((float4*)lwc1)[k * 32 + tx];
    #pragma unroll
    for (int r = 0; r < 8; ++r) {
      float xv = laggx[ty + 8 * r][k];
      tacc[r].x += xv * wv.x; tacc[r].y += xv * wv.y;
      tacc[r].z += xv * wv.z; tacc[r].w += xv * wv.w;
    }
  }
  #pragma unroll
  for (int r = 0; r < 8; ++r)
    *(float4*)&lt[ty + 8 * r][4 * tx] = tacc[r];
  __syncthreads();
  v2f acc2[16];
  #pragma unroll
  for (int r = 0; r < 16; ++r) acc2[r] = (v2f){0.f, 0.f};
  for (int kc = 0; kc < 16; ++kc) {
    float4 wreg[8];
    #pragma unroll
    for (int k = 0; k < 8; ++k)
      wreg[k] = *(const float4*)(Wf + (size_t)(kc * 8 + k) * HB + 4 * tx);
    #pragma unroll
    for (int kk = 0; kk < 8; kk += 4) {
      float4 xreg[8];
      #pragma unroll
      for (int r = 0; r < 8; ++r)
        xreg[r] = *(const float4*)&lt[ty + 8 * r][kc * 8 + kk];
      #pragma unroll
      for (int k2 = 0; k2 < 4; ++k2) {
        float4 wv = wreg[kk + k2];
        v2f wlo = {wv.x, wv.y}, whi = {wv.z, wv.w};
        #pragma unroll
        for (int r = 0; r < 8; ++r) {
          float xv = ((const float*)&xreg[r])[k2];
          v2f xvv = {xv, xv};
          acc2[2 * r]     += xvv * wlo;
          acc2[2 * r + 1] += xvv * whi;
        }
      }
    }
  }
  float4 bv = ((const float4*)bf0)[tx];
  float4 psum = make_float4(0.f, 0.f, 0.f, 0.f);
  float4 psq  = make_float4(0.f, 0.f, 0.f, 0.f);
  __syncthreads();
  #pragma unroll
  for (int r = 0; r < 8; ++r) {
    float4 v;
    v.x = fmaxf(acc2[2 * r].x + bv.x, 0.f);
    v.y = fmaxf(acc2[2 * r].y + bv.y, 0.f);
    v.z = fmaxf(acc2[2 * r + 1].x + bv.z, 0.f);
    v.w = fmaxf(acc2[2 * r + 1].y + bv.w, 0.f);
    psum.x += v.x; psum.y += v.y; psum.z += v.z; psum.w += v.w;
    psq.x += v.x * v.x; psq.y += v.y * v.y;
    psq.z += v.z * v.z; psq.w += v.w * v.w;
    *(float4*)(out + (size_t)(rowbase + ty + 8 * r) * HB + 4 * tx) = v;
  }
  red[ty][4 * tx + 0] = make_float2(psum.x, psq.x);
  red[ty][4 * tx + 1] = make_float2(psum.y, psq.y);
  red[ty][4 * tx + 2] = make_float2(psum.z, psq.z);
  red[ty][4 * tx + 3] = make_float2(psum.w, psq.w);
  __syncthreads();
  if (tid < 128) {
    float s = 0.f, q = 0.f;
    #pragma unroll
    for (int t = 0; t < 8; ++t) { s += red[t][tid].x; q += red[t][tid].y; }
    float* st = stat + ((blockIdx.x & 7) << 8);
    atomicAdd(&st[tid], s);
    atomicAdd(&st[128 + tid], q);
  }
}

// ---- standalone gather (no LDS, high occupancy): xagg = BN-affine weighted sum ----
__global__ __launch_bounds__(256) void gatherx_k(const float* __restrict__ Ap,
    const float* __restrict__ bnsc, const int* __restrict__ sel,
    const float* __restrict__ scale, const int* __restrict__ srowA,
    const float* __restrict__ snorm2, const int* __restrict__ off,
    const int* __restrict__ offe, const float* __restrict__ dis,
    float* __restrict__ xagg, int N) {
  int cpx = gridDim.x >> 3;
  int b = blockIdx.x;
  int bid = (b & 7) * cpx + (b >> 3);     // XCD-chunked swizzle
  int gid = bid * 256 + threadIdx.x;
  int node = gid >> 2;                    // 4 threads per node
  if (node >= N) return;
  int chq = (gid & 3) * 32;
  int e0 = off[node], e1 = offe[node];
  float dv = dis[node];
  float4 acc[8];
  float ssum;
  {
    float sc = scale[node] * dv * dv;     // self-loop term
    ssum = sc;
    const float* xr = Ap + (size_t)sel[node] * HB + chq;
    #pragma unroll
    for (int q = 0; q < 8; ++q) {
      float4 v = *(const float4*)(xr + 4 * q);
      acc[q].x = v.x * sc; acc[q].y = v.y * sc;
      acc[q].z = v.z * sc; acc[q].w = v.w * sc;
    }
  }
  for (int j = e0; j < e1; ++j) {
    float sc = snorm2[j];
    const float* xr = Ap + (size_t)srowA[j] * HB + chq;
    ssum += sc;
    #pragma unroll
    for (int q = 0; q < 8; ++q) {
      float4 v = *(const float4*)(xr + 4 * q);
      acc[q].x += v.x * sc; acc[q].y += v.y * sc;
      acc[q].z += v.z * sc; acc[q].w += v.w * sc;
    }
  }
  float* outp = xagg + (size_t)node * HB + chq;
  #pragma unroll
  for (int q = 0; q < 8; ++q) {
    float4 a  = *(const float4*)(bnsc + chq + 4 * q);
    float4 b8 = *(const float4*)(bnsc + 128 + chq + 4 * q);
    float4 o;
    o.x = a.x * acc[q].x + b8.x * ssum;
    o.y = a.y * acc[q].y + b8.y * ssum;
    o.z = a.z * acc[q].z + b8.z * ssum;
    o.w = a.w * acc[q].w + b8.w * ssum;
    *(float4*)(outp + 4 * q) = o;
  }
}

// ---- fused double gemm: out = relu((xagg@Wc + bc) @ Wf + bf), sharded bnstat ----
__global__ __launch_bounds__(256) void fc2_k(const float* __restrict__ xagg,
    const float* __restrict__ Wc, const float* __restrict__ bc0,
    const float* __restrict__ Wf, const float* __restrict__ bf0,
    float* __restrict__ out, int N, float* __restrict__ stat) {
  __shared__ float buf[64][XP];    // 33.8KB: xagg tile, then t tile
  float2 (*red)[128] = (float2(*)[128])buf;
  int tid = threadIdx.x;
  int tx = tid & 31, ty = tid >> 5;
  long rowbase = (long)blockIdx.x * 64;
  // ---- phase 1: coalesced tile load ----
  {
    int r = tid >> 2;
    int chq = (tid & 3) * 32;
    const float* xr = xagg + (rowbase + r) * HB + chq;
    #pragma unroll
    for (int q = 0; q < 8; ++q)
      *(float4*)&buf[r][chq + 4 * q] = *(const float4*)(xr + 4 * q);
  }
  __syncthreads();
  // ---- phase 2: t = buf @ Wc + bc ----
  {
    float4 bcv = ((const float4*)bc0)[tx];
    v2f acc2[16];
    #pragma unroll
    for (int r = 0; r < 8; ++r) {
      acc2[2 * r]     = (v2f){bcv.x, bcv.y};
      acc2[2 * r + 1] = (v2f){bcv.z, bcv.w};
    }
    for (int kc = 0; kc < 16; ++kc) {
      float4 wreg[8];
      #pragma unroll
      for (int k = 0; k < 8; ++k)
        wreg[k] = *(const float4*)(Wc + (size_t)(kc * 8 + k) * HB + 4 * tx);
      #pragma unroll
      for (int kk = 0; kk < 8; kk += 4) {
        float4 xreg[8];
        #pragma unroll
        for (int r = 0; r < 8; ++r)
          xreg[r] = *(const float4*)&buf[ty + 8 * r][kc * 8 + kk];
        #pragma unroll
        for (int k2 = 0; k2 < 4; ++k2) {
          float4 wv = wreg[kk + k2];
          v2f wlo = {wv.x, wv.y}, whi = {wv.z, wv.w};
          #pragma unroll
          for (int r = 0; r < 8; ++r) {
            float xv = ((const float*)&xreg[r])[k2];
            v2f xvv = {xv, xv};
            acc2[2 * r]     += xvv * wlo;
            acc2[2 * r + 1] += xvv * whi;
          }
        }
      }
    }
    __syncthreads();   // all xagg reads complete before t overwrites buf
    #pragma unroll
    for (int r = 0; r < 8; ++r) {
      float4 v;
      v.x = acc2[2 * r].x;     v.y = acc2[2 * r].y;
      v.z = acc2[2 * r + 1].x; v.w = acc2[2 * r + 1].y;
      *(float4*)&buf[ty + 8 * r][4 * tx] = v;
    }
  }
  __syncthreads();
  // ---- phase 3: out = relu(t @ Wf + bf), sharded bnstat ----
  v2f acc2[16];
  #pragma unroll
  for (int r = 0; r < 16; ++r) acc2[r] = (v2f){0.f, 0.f};
  for (int kc = 0; kc < 16; ++kc) {
    float4 wreg[8];
    #pragma unroll
    for (int k = 0; k < 8; ++k)
      wreg[k] = *(const float4*)(Wf + (size_t)(kc * 8 + k) * HB + 4 * tx);
    #pragma unroll
    for (int kk = 0; kk < 8; kk += 4) {
      float4 xreg[8];
      #pragma unroll
      for (int r = 0; r < 8; ++r)
        xreg[r] = *(const float4*)&buf[ty + 8 * r][kc * 8 + kk];
      #pragma unroll
      for (int k2 = 0; k2 < 4; ++k2) {
        float4 wv = wreg[kk + k2];
        v2f wlo = {wv.x, wv.y}, whi = {wv.z, wv.w};
        #pragma unroll
        for (int r = 0; r < 8; ++r) {
          float xv = ((const float*)&xreg[r])[k2];
          v2f xvv = {xv, xv};
          acc2[2 * r]     += xvv * wlo;
          acc2[2 * r + 1] += xvv * whi;
        }
      }
    }
  }
  float4 bv = ((const float4*)bf0)[tx];
  float4 psum = make_float4(0.f, 0.f, 0.f, 0.f);
  float4 psq  = make_float4(0.f, 0.f, 0.f, 0.f);
  __syncthreads();   // all t reads done before red overwrites buf
  #pragma unroll
  for (int r = 0; r < 8; ++r) {
    float4 v;
    v.x = fmaxf(acc2[2 * r].x + bv.x, 0.f);
    v.y = fmaxf(acc2[2 * r].y + bv.y, 0.f);
    v.z = fmaxf(acc2[2 * r + 1].x + bv.z, 0.f);
    v.w = fmaxf(acc2[2 * r + 1].y + bv.w, 0.f);
    psum.x += v.x; psum.y += v.y; psum.z += v.z; psum.w += v.w;
    psq.x += v.x * v.x; psq.y += v.y * v.y;
    psq.z += v.z * v.z; psq.w += v.w * v.w;
    *(float4*)(out + (size_t)(rowbase + ty + 8 * r) * HB + 4 * tx) = v;
  }
  red[ty][4 * tx + 0] = make_float2(psum.x, psq.x);
  red[ty][4 * tx + 1] = make_float2(psum.y, psq.y);
  red[ty][4 * tx + 2] = make_float2(psum.z, psq.z);
  red[ty][4 * tx + 3] = make_float2(psum.w, psq.w);
  __syncthreads();
  if (tid < 128) {
    float s = 0.f, q = 0.f;
    #pragma unroll
    for (int t = 0; t < 8; ++t) { s += red[t][tid].x; q += red[t][tid].y; }
    float* st = stat + (((int)blockIdx.x & 7) << 8);
    atomicAdd(&st[tid], s);
    atomicAdd(&st[128 + tid], q);
  }
}

// ---- fused per-graph CSR build (slab-based; folds sel/scale into payload) ----
__global__ __launch_bounds__(1024) void csr_build_k(const int* __restrict__ row,
    const int* __restrict__ col, const int* __restrict__ gcnt,
    const int* __restrict__ sel, const float* __restrict__ scale,
    float* __restrict__ dis, int* __restrict__ off, int* __restrict__ offe,
    int* __restrict__ srow, int* __restrict__ srowA,
    float* __restrict__ snorm, int n) {
  extern __shared__ int lds[];
  int* ldeg = lds;
  int* lsa  = lds + n;
  int* lsb  = lds + 2 * n;
  float* ldis = (float*)(lds + 3 * n);
  int g = blockIdx.x, tid = threadIdx.x;
  int e0 = g * SLAB, e1 = e0 + gcnt[g];
  int base = g * n;
  for (int i = tid; i < n; i += 1024) ldeg[i] = 0;
  __syncthreads();
  for (int e = e0 + tid; e < e1; e += 1024) atomicAdd(&ldeg[col[e] - base], 1);
  __syncthreads();
  for (int i = tid; i < n; i += 1024) {
    int d = ldeg[i];
    ldis[i] = rsqrtf((float)d + 1.f);
    lsa[i] = d;
  }
  __syncthreads();
  int* src = lsa; int* dst = lsb;
  for (int o = 1; o < n; o <<= 1) {
    for (int i = tid; i < n; i += 1024) dst[i] = src[i] + ((i >= o) ? src[i - o] : 0);
    __syncthreads();
    int* t = src; src = dst; dst = t;
  }
  for (int i = tid; i < n; i += 1024) {
    int d = ldeg[i];
    int ex = src[i] - d;
    off[base + i]  = e0 + ex;
    offe[base + i] = e0 + ex + d;
    ldeg[i] = ex;
    dis[base + i] = ldis[i];
  }
  __syncthreads();
  for (int e = e0 + tid; e < e1; e += 1024) {
    int r = row[e], c = col[e];
    int lc = c - base;
    int p = e0 + atomicAdd(&ldeg[lc], 1);
    srow[p] = r;
    float nm = ldis[r - base] * ldis[lc];
    if (sel) { srowA[p] = sel[r]; snorm[p] = nm * scale[r]; }
    else     { srowA[p] = r;      snorm[p] = nm; }
  }
}

// ---- layer-0: aggregate raw 7-channel X over CSR + self loop -> aggx[N][8] ----
__global__ __launch_bounds__(256) void agg7_k(const float* __restrict__ x,
    const int* __restrict__ srow, const float* __restrict__ snorm,
    const int* __restrict__ off, const int* __restrict__ offe,
    const float* __restrict__ dis, float* __restrict__ aggx, int N) {
  int cpx = gridDim.x >> 3;
  int b = blockIdx.x;
  int bid = (b & 7) * cpx + (b >> 3);
  int gid = bid * 256 + threadIdx.x;
  int node = gid >> 3, c = gid & 7;
  if (node >= N) return;
  float acc = 0.f;
  if (c < 7) {
    int s = off[node], e = offe[node];
    for (int j = s; j < e; ++j) acc += x[(size_t)srow[j] * 7 + c] * snorm[j];
    float d = dis[node];
    acc += x[(size_t)node * 7 + c] * d * d;
  }
  aggx[(size_t)node * 8 + c] = acc;
}

// ---- BN finalize from 8-sharded stat ----
__global__ __launch_bounds__(128) void bnfin_k(const float* __restrict__ stat8,
    const float* __restrict__ g, const float* __restrict__ b,
    float* __restrict__ sc, int N) {
  int c = threadIdx.x;
  if (c < 128) {
    float s = 0.f, q = 0.f;
    #pragma unroll
    for (int sh = 0; sh < 8; ++sh) {
      s += stat8[sh * 256 + c];
      q += stat8[sh * 256 + 128 + c];
    }
    float mu = s / N;
    float var = q / N - mu * mu;
    float a = g[c] * rsqrtf(var + 1e-5f);
    sc[c] = a;
    sc[128 + c] = b[c] - mu * a;
  }
}

// ---- score prep: read pre-BN h, apply affine in registers, dot with Ws1/Ws2 ----
__global__ __launch_bounds__(256) void score_prep_k(const float* __restrict__ h,
    const float* __restrict__ sc, const float* __restrict__ w1,
    const float* __restrict__ w2, float* __restrict__ selfs,
    float* __restrict__ t2, int N) {
  int gid = blockIdx.x * blockDim.x + threadIdx.x;
  int node = gid >> 6;
  if (node >= N) return;
  int lane = gid & 63, c = lane * 2;
  float2 v = *(const float2*)(h + (size_t)node * HB + c);
  v.x = v.x * sc[c] + sc[128 + c];
  v.y = v.y * sc[c + 1] + sc[128 + c + 1];
  float s1 = v.x * w1[c] + v.y * w1[c + 1];
  float s2 = v.x * w2[c] + v.y * w2[c + 1];
  #pragma unroll
  for (int off = 32; off > 0; off >>= 1) {
    s1 += __shfl_xor(s1, off);
    s2 += __shfl_xor(s2, off);
  }
  if (lane == 0) { selfs[node] = s1; t2[node] = s2; }
}

// ---- SAG score: selfs + CSR gather of t2 + bias ----
__global__ __launch_bounds__(256) void score_k(const float* __restrict__ selfs,
    const float* __restrict__ t2, const int* __restrict__ srow,
    const int* __restrict__ off, const int* __restrict__ offe,
    const float* __restrict__ bs, float* __restrict__ score, int N) {
  int i = blockIdx.x * blockDim.x + threadIdx.x;
  if (i >= N) return;
  float s = selfs[i] + bs[0];
  int e0 = off[i], e1 = offe[i];
  for (int j = e0; j < e1; ++j) s += t2[srow[j]];
  score[i] = s;
}

// ---- exact top-k by rank; bpg blocks per graph, 256 threads, 1 elem/thread ----
__global__ __launch_bounds__(256) void rank_topk_k(const float* __restrict__ score,
    int* __restrict__ inv, int* __restrict__ sel, float* __restrict__ scale,
    int n, int k, int bpg) {
  extern __shared__ float ls[];  // n floats
  int g = blockIdx.x / bpg, sub = blockIdx.x % bpg;
  int tid = threadIdx.x;
  const float* sg = score + (size_t)g * n;
  for (int i = tid; i < n; i += 256) ls[i] = sg[i];
  __syncthreads();
  int i0 = sub * 256 + tid;
  float s0 = ls[i0];
  int r0 = 0;
  for (int jb = 0; jb < n; jb += 4) {
    float4 v = *(const float4*)(ls + jb);
    r0 += (v.x > s0) || (v.x == s0 && (jb + 0) < i0);
    r0 += (v.y > s0) || (v.y == s0 && (jb + 1) < i0);
    r0 += (v.z > s0) || (v.z == s0 && (jb + 2) < i0);
    r0 += (v.w > s0) || (v.w == s0 && (jb + 3) < i0);
  }
  if (r0 < k) {
    inv[(size_t)g * n + i0] = g * k + r0;
    sel[(size_t)g * k + r0] = g * n + i0;
    scale[(size_t)g * k + r0] = tanhf(s0);
  } else inv[(size_t)g * n + i0] = -1;
}

// ---- gather kept rows with BN affine (final layer -> pool input) ----
__global__ __launch_bounds__(256) void gather_x_k(const float* __restrict__ h,
    const float* __restrict__ bnsc, const int* __restrict__ sel,
    const float* __restrict__ scale, float* __restrict__ xout, int M) {
  int gid = blockIdx.x * blockDim.x + threadIdx.x;
  int r = gid >> 5;
  if (r >= M) return;
  int ch = (gid & 31) * 4;
  int old = sel[r];
  float sc = scale[r];
  float4 v = *(const float4*)(h + (size_t)old * HB + ch);
  float4 a = *(const float4*)(bnsc + ch);
  float4 b = *(const float4*)(bnsc + 128 + ch);
  v.x = (v.x * a.x + b.x) * sc; v.y = (v.y * a.y + b.y) * sc;
  v.z = (v.z * a.z + b.z) * sc; v.w = (v.w * a.w + b.w) * sc;
  *(float4*)(xout + (size_t)r * HB + ch) = v;
}

// ---- single-pass slab compact: re-index, count, scatter (order-free) ----
__global__ __launch_bounds__(256) void cmp_k(const int* __restrict__ row,
    const int* __restrict__ col, const int* __restrict__ inv,
    const int* __restrict__ gcntCur, int* __restrict__ nrow,
    int* __restrict__ ncol, int* __restrict__ gcntNxt) {
  int g = blockIdx.x >> 6;
  int eloc = ((blockIdx.x & 63) << 8) + threadIdx.x;
  int cnt = gcntCur[g];
  if (((blockIdx.x & 63) << 8) >= cnt) return;   // whole block out of range
  long e = (long)g * SLAB + eloc;
  bool valid = false; int nr = 0, nc = 0;
  if (eloc < cnt) {
    nr = inv[row[e]]; nc = inv[col[e]];
    valid = (nr >= 0) && (nc >= 0);
  }
  unsigned long long mask = __ballot(valid);
  int lane = threadIdx.x & 63, wid = threadIdx.x >> 6;
  __shared__ int ws[4];
  __shared__ int base;
  if (lane == 0) ws[wid] = __popcll(mask);
  __syncthreads();
  if (threadIdx.x == 0) {
    int a = ws[0], b = ws[1], c2 = ws[2], d = ws[3];
    int tot = a + b + c2 + d;
    base = tot ? atomicAdd(&gcntNxt[g], tot) : 0;
    ws[0] = 0; ws[1] = a; ws[2] = a + b; ws[3] = a + b + c2;
  }
  __syncthreads();
  if (valid) {
    unsigned long long lt = ((unsigned long long)1 << lane) - 1;
    long o = (long)g * SLAB + base + ws[wid] + (int)__popcll(mask & lt);
    nrow[o] = nr;
    ncol[o] = nc;
  }
}

// ---- final mean pool ----
__global__ __launch_bounds__(128) void pool_k(const float* __restrict__ x,
    float* __restrict__ out, int n) {
  int g = blockIdx.x, c = threadIdx.x;
  float s = 0.f;
  for (int r = 0; r < n; ++r) s += x[((size_t)g * n + r) * HB + c];
  out[g * HB + c] = s / n;
}

extern "C" void kernel_launch(void* const* d_in, const int* in_sizes, int n_in,
                              void* d_out, int out_size, void* d_ws, size_t ws_size,
                              hipStream_t stream) {
  const float* x_in = (const float*)d_in[0];
  const int*   ei   = (const int*)d_in[1];
  const float* Wc1  = (const float*)d_in[3];
  const float* Wc   = (const float*)d_in[4];
  const float* bc   = (const float*)d_in[5];
  const float* Wf   = (const float*)d_in[6];
  const float* bf   = (const float*)d_in[7];
  const float* bng  = (const float*)d_in[8];
  const float* bnb  = (const float*)d_in[9];
  const float* Ws1  = (const float*)d_in[10];
  const float* Ws2  = (const float*)d_in[11];
  const float* bs   = (const float*)d_in[12];

  const int N0 = 131072, E = NE;
  char* p = (char*)d_ws;
  auto alloc = [&](size_t bytes) -> char* {
    char* r = p; p += (bytes + 255) & ~(size_t)255; return r;
  };
  float* A    = (float*)alloc((size_t)N0 * HB * 4);       // layer io ping
  float* Bb   = (float*)alloc((size_t)N0 * HB * 4);       // layer io pong
  float* Cc   = (float*)alloc((size_t)(N0 / 2) * HB * 4); // pool input
  float* xagg = (float*)alloc((size_t)(N0 / 2) * HB * 4); // gathered features
  float* aggx = (float*)alloc((size_t)N0 * 8 * 4);
  int*   rowA = (int*)alloc((size_t)E * 4);
  int*   colA = (int*)alloc((size_t)E * 4);
  int*   rowB = (int*)alloc((size_t)E * 4);
  int*   colB = (int*)alloc((size_t)E * 4);
  int*   srowA= (int*)alloc((size_t)E * 4);   // folded payload: Ap row per edge
  float* dis  = (float*)alloc((size_t)N0 * 4);
  float* selfs= (float*)alloc((size_t)N0 * 4);
  float* t2v  = (float*)alloc((size_t)N0 * 4);
  float* score= (float*)alloc((size_t)N0 * 4);
  int*   inv  = (int*)alloc((size_t)N0 * 4);
  int*   off  = (int*)alloc((size_t)N0 * 4);
  int*   offe = (int*)alloc((size_t)N0 * 4);
  int*   sel  = (int*)alloc((size_t)(N0 / 2) * 4);
  float* scale= (float*)alloc((size_t)(N0 / 2) * 4);
  int*   gcntL= (int*)alloc(4 * NB * 4);     // per-layer graph edge counts
  float* stat8= (float*)alloc(4 * 8 * 256 * 4);  // per-layer 8-sharded BN stats
  float* bnsc = (float*)alloc(256 * 4);

  hipMemsetAsync(stat8, 0, 4 * 8 * 256 * 4, stream);
  hipMemsetAsync(gcntL, 0, 4 * NB * 4, stream);

  init_edges_k<<<E / 256, 256, 0, stream>>>(ei, rowA, colA, gcntL, E);

  int* rowCur = rowA; int* colCur = colA;
  int* rowNxt = rowB; int* colNxt = colB;

  int n = 2048;
  for (int i = 0; i < 4; ++i) {
    int N = NB * n, khalf = n >> 1;
    float* statL = stat8 + (size_t)i * 8 * 256;
    // layer io ping-pong: L0 out=A, L1 A->Bb, L2 Bb->A, L3 A->Bb
    const float* Xin  = (i == 2) ? Bb : A;
    float*       Xout = (i == 0 || i == 2) ? A : Bb;
    // CSR payload srow/snorm aliases the INACTIVE edge double-buffer
    // (rowNxt/colNxt); srowA is dedicated. All stream-ordered.
    int*   srow  = rowNxt;
    float* snorm = (float*)colNxt;
    csr_build_k<<<NB, 1024, (size_t)16 * n, stream>>>(
        rowCur, colCur, gcntL + i * NB, (i == 0) ? nullptr : sel,
        (i == 0) ? nullptr : scale, dis, off, offe, srow, srowA, snorm, n);
    if (i == 0) {
      agg7_k<<<N / 32, 256, 0, stream>>>(x_in, srow, snorm, off, offe, dis, aggx, N);
      conv_fc0_k<<<N / 64, 256, 0, stream>>>(aggx, Wc1, bc, Wf, bf, Xout, N, statL);
    } else {
      // split: high-occupancy gather -> xagg, then LDS double-gemm
      gatherx_k<<<N / 64, 256, 0, stream>>>(
          Xin, bnsc, sel, scale, srowA, snorm, off, offe, dis, xagg, N);
      fc2_k<<<N / 64, 256, 0, stream>>>(
          xagg, Wc + (size_t)(i - 1) * HB * HB, bc + (size_t)i * HB,
          Wf + (size_t)i * HB * HB, bf + (size_t)i * HB, Xout, N, statL);
    }
    bnfin_k<<<1, 128, 0, stream>>>(statL, bng + (size_t)i * HB, bnb + (size_t)i * HB, bnsc, N);
    score_prep_k<<<N / 4, 256, 0, stream>>>(
        Xout, bnsc, Ws1 + (size_t)i * HB, Ws2 + (size_t)i * HB, selfs, t2v, N);
    score_k<<<(N + 255) / 256, 256, 0, stream>>>(
        selfs, t2v, srow, off, offe, bs + i, score, N);
    int bpg = n / 256;
    rank_topk_k<<<NB * bpg, 256, (size_t)n * 4, stream>>>(
        score, inv, sel, scale, n, khalf, bpg);
    if (i < 3) {
      cmp_k<<<NB * 64, 256, 0, stream>>>(rowCur, colCur, inv, gcntL + i * NB,
                                         rowNxt, colNxt, gcntL + (i + 1) * NB);
      int* t;
      t = rowCur; rowCur = rowNxt; rowNxt = t;
      t = colCur; colCur = colNxt; colNxt = t;
    } else {
      gather_x_k<<<(NB * khalf) / 8, 256, 0, stream>>>(
          Xout, bnsc, sel, scale, Cc, NB * khalf);
    }
    n = khalf;
  }
  pool_k<<<NB, 128, 0, stream>>>(Cc, (float*)d_out, n);
}

// Round 20
// 582.206 us; speedup vs baseline: 1.1094x; 1.1094x over previous
//
#include <hip/hip_runtime.h>
#include <cstdint>

#define HB 128    // hidden size
#define NB 64     // graphs per batch
#define NE 1048576
#define SLAB 16384  // per-graph edge slab (NE/NB), constant across layers
#define XP 132    // padded LDS row stride (floats)

typedef float v2f __attribute__((ext_vector_type(2)));

// ---- init edge arrays + layer-0 edge-count metadata ----
__global__ __launch_bounds__(256) void init_edges_k(const int* __restrict__ ei,
    int* __restrict__ row, int* __restrict__ col, int* __restrict__ gcnt0, int E) {
  int e = blockIdx.x * blockDim.x + threadIdx.x;
  if (e < E) { row[e] = ei[e]; col[e] = ei[E + e]; }
  if (blockIdx.x == 0 && threadIdx.x < NB) gcnt0[threadIdx.x] = SLAB;
}

// ---- fused layer-0 dense chain: out = relu((aggx@Wc1 + bc) @ Wf + bf) ----
__global__ __launch_bounds__(256) void conv_fc0_k(const float* __restrict__ aggx,
    const float* __restrict__ Wc1, const float* __restrict__ bc0,
    const float* __restrict__ Wf, const float* __restrict__ bf0,
    float* __restrict__ out, int N, float* __restrict__ stat) {
  __shared__ float lt[64][128];      // 32KB; red aliases front 8KB after final sync
  __shared__ float laggx[64][8];
  __shared__ float lwc1[7 * 128];
  float2 (*red)[128] = (float2(*)[128])lt;
  int tid = threadIdx.x;
  int tx = tid & 31, ty = tid >> 5;
  long rowbase = (long)blockIdx.x * 64;
  for (int i = tid; i < 7 * 32; i += 256)
    ((float4*)lwc1)[i] = ((const float4*)Wc1)[i];
  if (tid < 128) {
    int lr = tid >> 1, lq = (tid & 1) * 4;
    *(float4*)&laggx[lr][lq] = *(const float4*)(aggx + (rowbase + lr) * 8 + lq);
  }
  __syncthreads();
  float4 tacc[8];
  float4 bcv = ((const float4*)bc0)[tx];
  #pragma unroll
  for (int r = 0; r < 8; ++r) tacc[r] = bcv;
  #pragma unroll
  for (int k = 0; k < 7; ++k) {
    float4 wv = ((float4*)lwc1)[k * 32 + tx];
    #pragma unroll
    for (int r = 0; r < 8; ++r) {
      float xv = laggx[ty + 8 * r][k];
      tacc[r].x += xv * wv.x; tacc[r].y += xv * wv.y;
      tacc[r].z += xv * wv.z; tacc[r].w += xv * wv.w;
    }
  }
  #pragma unroll
  for (int r = 0; r < 8; ++r)
    *(float4*)&lt[ty + 8 * r][4 * tx] = tacc[r];
  __syncthreads();
  v2f acc2[16];
  #pragma unroll
  for (int r = 0; r < 16; ++r) acc2[r] = (v2f){0.f, 0.f};
  for (int kc = 0; kc < 16; ++kc) {
    float4 wreg[8];
    #pragma unroll
    for (int k = 0; k < 8; ++k)
      wreg[k] = *(const float4*)(Wf + (size_t)(kc * 8 + k) * HB + 4 * tx);
    #pragma unroll
    for (int kk = 0; kk < 8; kk += 4) {
      float4 xreg[8];
      #pragma unroll
      for (int r = 0; r < 8; ++r)
        xreg[r] = *(const float4*)&lt[ty + 8 * r][kc * 8 + kk];
      #pragma unroll
      for (int k2 = 0; k2 < 4; ++k2) {
        float4 wv = wreg[kk + k2];
        v2f wlo = {wv.x, wv.y}, whi = {wv.z, wv.w};
        #pragma unroll
        for (int r = 0; r < 8; ++r) {
          float xv = ((const float*)&xreg[r])[k2];
          v2f xvv = {xv, xv};
          acc2[2 * r]     += xvv * wlo;
          acc2[2 * r + 1] += xvv * whi;
        }
      }
    }
  }
  float4 bv = ((const float4*)bf0)[tx];
  float4 psum = make_float4(0.f, 0.f, 0.f, 0.f);
  float4 psq  = make_float4(0.f, 0.f, 0.f, 0.f);
  __syncthreads();
  #pragma unroll
  for (int r = 0; r < 8; ++r) {
    float4 v;
    v.x = fmaxf(acc2[2 * r].x + bv.x, 0.f);
    v.y = fmaxf(acc2[2 * r].y + bv.y, 0.f);
    v.z = fmaxf(acc2[2 * r + 1].x + bv.z, 0.f);
    v.w = fmaxf(acc2[2 * r + 1].y + bv.w, 0.f);
    psum.x += v.x; psum.y += v.y; psum.z += v.z; psum.w += v.w;
    psq.x += v.x * v.x; psq.y += v.y * v.y;
    psq.z += v.z * v.z; psq.w += v.w * v.w;
    *(float4*)(out + (size_t)(rowbase + ty + 8 * r) * HB + 4 * tx) = v;
  }
  red[ty][4 * tx + 0] = make_float2(psum.x, psq.x);
  red[ty][4 * tx + 1] = make_float2(psum.y, psq.y);
  red[ty][4 * tx + 2] = make_float2(psum.z, psq.z);
  red[ty][4 * tx + 3] = make_float2(psum.w, psq.w);
  __syncthreads();
  if (tid < 128) {
    float s = 0.f, q = 0.f;
    #pragma unroll
    for (int t = 0; t < 8; ++t) { s += red[t][tid].x; q += red[t][tid].y; }
    float* st = stat + ((blockIdx.x & 7) << 8);
    atomicAdd(&st[tid], s);
    atomicAdd(&st[128 + tid], q);
  }
}

// ---- fused layer>=1: out = relu((xagg@Wc + bc) @ Wf + bf), sharded bnstat ----
__global__ __launch_bounds__(256) void conv_fc_k(const float* __restrict__ Ap,
    const float* __restrict__ bnsc, const int* __restrict__ sel,
    const float* __restrict__ scale, const int* __restrict__ srow,
    const float* __restrict__ snorm, const int* __restrict__ off,
    const int* __restrict__ offe, const float* __restrict__ dis,
    const float* __restrict__ Wc, const float* __restrict__ bc0,
    const float* __restrict__ Wf, const float* __restrict__ bf0,
    float* __restrict__ out, int N, float* __restrict__ stat) {
  __shared__ float buf[64][XP];    // 33.8KB: xagg tile, then t tile
  float2 (*red)[128] = (float2(*)[128])buf;
  int tid = threadIdx.x;
  int tx = tid & 31, ty = tid >> 5;
  long cpx = gridDim.x >> 3;       // grid divisible by 8
  long bb = ((long)blockIdx.x & 7) * cpx + ((long)blockIdx.x >> 3);
  long rowbase = bb * 64;
  // ---- phase 1: CSR gather + BN affine + scale -> buf (xagg) ----
  {
    int r = tid >> 2;              // row 0..63
    int chq = (tid & 3) * 32;      // 32 channels per thread
    int node = rowbase + r;
    float4 av[8], bv8[8];
    #pragma unroll
    for (int q = 0; q < 8; ++q) {
      av[q]  = *(const float4*)(bnsc + chq + 4 * q);
      bv8[q] = *(const float4*)(bnsc + 128 + chq + 4 * q);
    }
    int e0 = off[node], e1 = offe[node];
    float dv = dis[node];
    float4 acc[8];
    {
      float sc = scale[node] * dv * dv;    // self-loop term
      const float* xr = Ap + (size_t)sel[node] * HB + chq;
      #pragma unroll
      for (int q = 0; q < 8; ++q) {
        float4 v = *(const float4*)(xr + 4 * q);
        acc[q].x = (v.x * av[q].x + bv8[q].x) * sc;
        acc[q].y = (v.y * av[q].y + bv8[q].y) * sc;
        acc[q].z = (v.z * av[q].z + bv8[q].z) * sc;
        acc[q].w = (v.w * av[q].w + bv8[q].w) * sc;
      }
    }
    for (int j = e0; j < e1; ++j) {
      int srcn = srow[j];
      float sc = snorm[j] * scale[srcn];
      const float* xr = Ap + (size_t)sel[srcn] * HB + chq;
      #pragma unroll
      for (int q = 0; q < 8; ++q) {
        float4 v = *(const float4*)(xr + 4 * q);
        acc[q].x += (v.x * av[q].x + bv8[q].x) * sc;
        acc[q].y += (v.y * av[q].y + bv8[q].y) * sc;
        acc[q].z += (v.z * av[q].z + bv8[q].z) * sc;
        acc[q].w += (v.w * av[q].w + bv8[q].w) * sc;
      }
    }
    #pragma unroll
    for (int q = 0; q < 8; ++q) *(float4*)&buf[r][chq + 4 * q] = acc[q];
  }
  __syncthreads();
  // ---- phase 2: t = buf @ Wc + bc ----
  {
    float4 bcv = ((const float4*)bc0)[tx];
    v2f acc2[16];
    #pragma unroll
    for (int r = 0; r < 8; ++r) {
      acc2[2 * r]     = (v2f){bcv.x, bcv.y};
      acc2[2 * r + 1] = (v2f){bcv.z, bcv.w};
    }
    for (int kc = 0; kc < 16; ++kc) {
      float4 wreg[8];
      #pragma unroll
      for (int k = 0; k < 8; ++k)
        wreg[k] = *(const float4*)(Wc + (size_t)(kc * 8 + k) * HB + 4 * tx);
      #pragma unroll
      for (int kk = 0; kk < 8; kk += 4) {
        float4 xreg[8];
        #pragma unroll
        for (int r = 0; r < 8; ++r)
          xreg[r] = *(const float4*)&buf[ty + 8 * r][kc * 8 + kk];
        #pragma unroll
        for (int k2 = 0; k2 < 4; ++k2) {
          float4 wv = wreg[kk + k2];
          v2f wlo = {wv.x, wv.y}, whi = {wv.z, wv.w};
          #pragma unroll
          for (int r = 0; r < 8; ++r) {
            float xv = ((const float*)&xreg[r])[k2];
            v2f xvv = {xv, xv};
            acc2[2 * r]     += xvv * wlo;
            acc2[2 * r + 1] += xvv * whi;
          }
        }
      }
    }
    __syncthreads();   // all xagg reads complete before t overwrites buf
    #pragma unroll
    for (int r = 0; r < 8; ++r) {
      float4 v;
      v.x = acc2[2 * r].x;     v.y = acc2[2 * r].y;
      v.z = acc2[2 * r + 1].x; v.w = acc2[2 * r + 1].y;
      *(float4*)&buf[ty + 8 * r][4 * tx] = v;
    }
  }
  __syncthreads();
  // ---- phase 3: out = relu(t @ Wf + bf), sharded bnstat ----
  v2f acc2[16];
  #pragma unroll
  for (int r = 0; r < 16; ++r) acc2[r] = (v2f){0.f, 0.f};
  for (int kc = 0; kc < 16; ++kc) {
    float4 wreg[8];
    #pragma unroll
    for (int k = 0; k < 8; ++k)
      wreg[k] = *(const float4*)(Wf + (size_t)(kc * 8 + k) * HB + 4 * tx);
    #pragma unroll
    for (int kk = 0; kk < 8; kk += 4) {
      float4 xreg[8];
      #pragma unroll
      for (int r = 0; r < 8; ++r)
        xreg[r] = *(const float4*)&buf[ty + 8 * r][kc * 8 + kk];
      #pragma unroll
      for (int k2 = 0; k2 < 4; ++k2) {
        float4 wv = wreg[kk + k2];
        v2f wlo = {wv.x, wv.y}, whi = {wv.z, wv.w};
        #pragma unroll
        for (int r = 0; r < 8; ++r) {
          float xv = ((const float*)&xreg[r])[k2];
          v2f xvv = {xv, xv};
          acc2[2 * r]     += xvv * wlo;
          acc2[2 * r + 1] += xvv * whi;
        }
      }
    }
  }
  float4 bv = ((const float4*)bf0)[tx];
  float4 psum = make_float4(0.f, 0.f, 0.f, 0.f);
  float4 psq  = make_float4(0.f, 0.f, 0.f, 0.f);
  __syncthreads();   // all t reads done before red overwrites buf
  #pragma unroll
  for (int r = 0; r < 8; ++r) {
    float4 v;
    v.x = fmaxf(acc2[2 * r].x + bv.x, 0.f);
    v.y = fmaxf(acc2[2 * r].y + bv.y, 0.f);
    v.z = fmaxf(acc2[2 * r + 1].x + bv.z, 0.f);
    v.w = fmaxf(acc2[2 * r + 1].y + bv.w, 0.f);
    psum.x += v.x; psum.y += v.y; psum.z += v.z; psum.w += v.w;
    psq.x += v.x * v.x; psq.y += v.y * v.y;
    psq.z += v.z * v.z; psq.w += v.w * v.w;
    *(float4*)(out + (size_t)(rowbase + ty + 8 * r) * HB + 4 * tx) = v;
  }
  red[ty][4 * tx + 0] = make_float2(psum.x, psq.x);
  red[ty][4 * tx + 1] = make_float2(psum.y, psq.y);
  red[ty][4 * tx + 2] = make_float2(psum.z, psq.z);
  red[ty][4 * tx + 3] = make_float2(psum.w, psq.w);
  __syncthreads();
  if (tid < 128) {
    float s = 0.f, q = 0.f;
    #pragma unroll
    for (int t = 0; t < 8; ++t) { s += red[t][tid].x; q += red[t][tid].y; }
    float* st = stat + (((int)blockIdx.x & 7) << 8);
    atomicAdd(&st[tid], s);
    atomicAdd(&st[128 + tid], q);
  }
}

// ---- fused per-graph CSR build (slab-based; writes start+end per node) ----
__global__ __launch_bounds__(1024) void csr_build_k(const int* __restrict__ row,
    const int* __restrict__ col, const int* __restrict__ gcnt,
    float* __restrict__ dis, int* __restrict__ off, int* __restrict__ offe,
    int* __restrict__ srow, float* __restrict__ snorm, int n) {
  extern __shared__ int lds[];
  int* ldeg = lds;
  int* lsa  = lds + n;
  int* lsb  = lds + 2 * n;
  float* ldis = (float*)(lds + 3 * n);
  int g = blockIdx.x, tid = threadIdx.x;
  int e0 = g * SLAB, e1 = e0 + gcnt[g];
  int base = g * n;
  for (int i = tid; i < n; i += 1024) ldeg[i] = 0;
  __syncthreads();
  for (int e = e0 + tid; e < e1; e += 1024) atomicAdd(&ldeg[col[e] - base], 1);
  __syncthreads();
  for (int i = tid; i < n; i += 1024) {
    int d = ldeg[i];
    ldis[i] = rsqrtf((float)d + 1.f);
    lsa[i] = d;
  }
  __syncthreads();
  int* src = lsa; int* dst = lsb;
  for (int o = 1; o < n; o <<= 1) {
    for (int i = tid; i < n; i += 1024) dst[i] = src[i] + ((i >= o) ? src[i - o] : 0);
    __syncthreads();
    int* t = src; src = dst; dst = t;
  }
  for (int i = tid; i < n; i += 1024) {
    int d = ldeg[i];
    int ex = src[i] - d;
    off[base + i]  = e0 + ex;
    offe[base + i] = e0 + ex + d;
    ldeg[i] = ex;
    dis[base + i] = ldis[i];
  }
  __syncthreads();
  for (int e = e0 + tid; e < e1; e += 1024) {
    int r = row[e], c = col[e];
    int lc = c - base;
    int p = e0 + atomicAdd(&ldeg[lc], 1);
    srow[p] = r;
    snorm[p] = ldis[r - base] * ldis[lc];
  }
}

// ---- layer-0: aggregate raw 7-channel X over CSR + self loop -> aggx[N][8] ----
__global__ __launch_bounds__(256) void agg7_k(const float* __restrict__ x,
    const int* __restrict__ srow, const float* __restrict__ snorm,
    const int* __restrict__ off, const int* __restrict__ offe,
    const float* __restrict__ dis, float* __restrict__ aggx, int N) {
  int cpx = gridDim.x >> 3;
  int b = blockIdx.x;
  int bid = (b & 7) * cpx + (b >> 3);
  int gid = bid * 256 + threadIdx.x;
  int node = gid >> 3, c = gid & 7;
  if (node >= N) return;
  float acc = 0.f;
  if (c < 7) {
    int s = off[node], e = offe[node];
    for (int j = s; j < e; ++j) acc += x[(size_t)srow[j] * 7 + c] * snorm[j];
    float d = dis[node];
    acc += x[(size_t)node * 7 + c] * d * d;
  }
  aggx[(size_t)node * 8 + c] = acc;
}

// ---- BN finalize from 8-sharded stat ----
__global__ __launch_bounds__(128) void bnfin_k(const float* __restrict__ stat8,
    const float* __restrict__ g, const float* __restrict__ b,
    float* __restrict__ sc, int N) {
  int c = threadIdx.x;
  if (c < 128) {
    float s = 0.f, q = 0.f;
    #pragma unroll
    for (int sh = 0; sh < 8; ++sh) {
      s += stat8[sh * 256 + c];
      q += stat8[sh * 256 + 128 + c];
    }
    float mu = s / N;
    float var = q / N - mu * mu;
    float a = g[c] * rsqrtf(var + 1e-5f);
    sc[c] = a;
    sc[128 + c] = b[c] - mu * a;
  }
}

// ---- score prep: read pre-BN h, apply affine in registers, dot with Ws1/Ws2 ----
__global__ __launch_bounds__(256) void score_prep_k(const float* __restrict__ h,
    const float* __restrict__ sc, const float* __restrict__ w1,
    const float* __restrict__ w2, float* __restrict__ selfs,
    float* __restrict__ t2, int N) {
  int gid = blockIdx.x * blockDim.x + threadIdx.x;
  int node = gid >> 6;
  if (node >= N) return;
  int lane = gid & 63, c = lane * 2;
  float2 v = *(const float2*)(h + (size_t)node * HB + c);
  v.x = v.x * sc[c] + sc[128 + c];
  v.y = v.y * sc[c + 1] + sc[128 + c + 1];
  float s1 = v.x * w1[c] + v.y * w1[c + 1];
  float s2 = v.x * w2[c] + v.y * w2[c + 1];
  #pragma unroll
  for (int off = 32; off > 0; off >>= 1) {
    s1 += __shfl_xor(s1, off);
    s2 += __shfl_xor(s2, off);
  }
  if (lane == 0) { selfs[node] = s1; t2[node] = s2; }
}

// ---- SAG score: selfs + CSR gather of t2 + bias ----
__global__ __launch_bounds__(256) void score_k(const float* __restrict__ selfs,
    const float* __restrict__ t2, const int* __restrict__ srow,
    const int* __restrict__ off, const int* __restrict__ offe,
    const float* __restrict__ bs, float* __restrict__ score, int N) {
  int i = blockIdx.x * blockDim.x + threadIdx.x;
  if (i >= N) return;
  float s = selfs[i] + bs[0];
  int e0 = off[i], e1 = offe[i];
  for (int j = e0; j < e1; ++j) s += t2[srow[j]];
  score[i] = s;
}

// ---- exact top-k by rank; bpg blocks per graph, 256 threads, 1 elem/thread ----
__global__ __launch_bounds__(256) void rank_topk_k(const float* __restrict__ score,
    int* __restrict__ inv, int* __restrict__ sel, float* __restrict__ scale,
    int n, int k, int bpg) {
  extern __shared__ float ls[];  // n floats
  int g = blockIdx.x / bpg, sub = blockIdx.x % bpg;
  int tid = threadIdx.x;
  const float* sg = score + (size_t)g * n;
  for (int i = tid; i < n; i += 256) ls[i] = sg[i];
  __syncthreads();
  int i0 = sub * 256 + tid;
  float s0 = ls[i0];
  int r0 = 0;
  for (int jb = 0; jb < n; jb += 4) {
    float4 v = *(const float4*)(ls + jb);
    r0 += (v.x > s0) || (v.x == s0 && (jb + 0) < i0);
    r0 += (v.y > s0) || (v.y == s0 && (jb + 1) < i0);
    r0 += (v.z > s0) || (v.z == s0 && (jb + 2) < i0);
    r0 += (v.w > s0) || (v.w == s0 && (jb + 3) < i0);
  }
  if (r0 < k) {
    inv[(size_t)g * n + i0] = g * k + r0;
    sel[(size_t)g * k + r0] = g * n + i0;
    scale[(size_t)g * k + r0] = tanhf(s0);
  } else inv[(size_t)g * n + i0] = -1;
}

// ---- gather kept rows with BN affine (final layer -> pool input) ----
__global__ __launch_bounds__(256) void gather_x_k(const float* __restrict__ h,
    const float* __restrict__ bnsc, const int* __restrict__ sel,
    const float* __restrict__ scale, float* __restrict__ xout, int M) {
  int gid = blockIdx.x * blockDim.x + threadIdx.x;
  int r = gid >> 5;
  if (r >= M) return;
  int ch = (gid & 31) * 4;
  int old = sel[r];
  float sc = scale[r];
  float4 v = *(const float4*)(h + (size_t)old * HB + ch);
  float4 a = *(const float4*)(bnsc + ch);
  float4 b = *(const float4*)(bnsc + 128 + ch);
  v.x = (v.x * a.x + b.x) * sc; v.y = (v.y * a.y + b.y) * sc;
  v.z = (v.z * a.z + b.z) * sc; v.w = (v.w * a.w + b.w) * sc;
  *(float4*)(xout + (size_t)r * HB + ch) = v;
}

// ---- single-pass slab compact: re-index, count, scatter (order-free) ----
__global__ __launch_bounds__(256) void cmp_k(const int* __restrict__ row,
    const int* __restrict__ col, const int* __restrict__ inv,
    const int* __restrict__ gcntCur, int* __restrict__ nrow,
    int* __restrict__ ncol, int* __restrict__ gcntNxt) {
  int g = blockIdx.x >> 6;
  int eloc = ((blockIdx.x & 63) << 8) + threadIdx.x;
  int cnt = gcntCur[g];
  if (((blockIdx.x & 63) << 8) >= cnt) return;   // whole block out of range
  long e = (long)g * SLAB + eloc;
  bool valid = false; int nr = 0, nc = 0;
  if (eloc < cnt) {
    nr = inv[row[e]]; nc = inv[col[e]];
    valid = (nr >= 0) && (nc >= 0);
  }
  unsigned long long mask = __ballot(valid);
  int lane = threadIdx.x & 63, wid = threadIdx.x >> 6;
  __shared__ int ws[4];
  __shared__ int base;
  if (lane == 0) ws[wid] = __popcll(mask);
  __syncthreads();
  if (threadIdx.x == 0) {
    int a = ws[0], b = ws[1], c2 = ws[2], d = ws[3];
    int tot = a + b + c2 + d;
    base = tot ? atomicAdd(&gcntNxt[g], tot) : 0;
    ws[0] = 0; ws[1] = a; ws[2] = a + b; ws[3] = a + b + c2;
  }
  __syncthreads();
  if (valid) {
    unsigned long long lt = ((unsigned long long)1 << lane) - 1;
    long o = (long)g * SLAB + base + ws[wid] + (int)__popcll(mask & lt);
    nrow[o] = nr;
    ncol[o] = nc;
  }
}

// ---- final mean pool ----
__global__ __launch_bounds__(128) void pool_k(const float* __restrict__ x,
    float* __restrict__ out, int n) {
  int g = blockIdx.x, c = threadIdx.x;
  float s = 0.f;
  for (int r = 0; r < n; ++r) s += x[((size_t)g * n + r) * HB + c];
  out[g * HB + c] = s / n;
}

extern "C" void kernel_launch(void* const* d_in, const int* in_sizes, int n_in,
                              void* d_out, int out_size, void* d_ws, size_t ws_size,
                              hipStream_t stream) {
  const float* x_in = (const float*)d_in[0];
  const int*   ei   = (const int*)d_in[1];
  const float* Wc1  = (const float*)d_in[3];
  const float* Wc   = (const float*)d_in[4];
  const float* bc   = (const float*)d_in[5];
  const float* Wf   = (const float*)d_in[6];
  const float* bf   = (const float*)d_in[7];
  const float* bng  = (const float*)d_in[8];
  const float* bnb  = (const float*)d_in[9];
  const float* Ws1  = (const float*)d_in[10];
  const float* Ws2  = (const float*)d_in[11];
  const float* bs   = (const float*)d_in[12];

  const int N0 = 131072, E = NE;
  char* p = (char*)d_ws;
  auto alloc = [&](size_t bytes) -> char* {
    char* r = p; p += (bytes + 255) & ~(size_t)255; return r;
  };
  float* A    = (float*)alloc((size_t)N0 * HB * 4);       // layer io ping
  float* Bb   = (float*)alloc((size_t)N0 * HB * 4);       // layer io pong
  float* Cc   = (float*)alloc((size_t)(N0 / 2) * HB * 4); // pool input
  float* aggx = (float*)alloc((size_t)N0 * 8 * 4);
  int*   rowA = (int*)alloc((size_t)E * 4);
  int*   colA = (int*)alloc((size_t)E * 4);
  int*   rowB = (int*)alloc((size_t)E * 4);
  int*   colB = (int*)alloc((size_t)E * 4);
  float* dis  = (float*)alloc((size_t)N0 * 4);
  float* selfs= (float*)alloc((size_t)N0 * 4);
  float* t2v  = (float*)alloc((size_t)N0 * 4);
  float* score= (float*)alloc((size_t)N0 * 4);
  int*   inv  = (int*)alloc((size_t)N0 * 4);
  int*   off  = (int*)alloc((size_t)N0 * 4);
  int*   offe = (int*)alloc((size_t)N0 * 4);
  int*   sel  = (int*)alloc((size_t)(N0 / 2) * 4);
  float* scale= (float*)alloc((size_t)(N0 / 2) * 4);
  int*   gcntL= (int*)alloc(4 * NB * 4);     // per-layer graph edge counts
  float* stat8= (float*)alloc(4 * 8 * 256 * 4);  // per-layer 8-sharded BN stats
  float* bnsc = (float*)alloc(256 * 4);

  hipMemsetAsync(stat8, 0, 4 * 8 * 256 * 4, stream);
  hipMemsetAsync(gcntL, 0, 4 * NB * 4, stream);

  init_edges_k<<<E / 256, 256, 0, stream>>>(ei, rowA, colA, gcntL, E);

  int* rowCur = rowA; int* colCur = colA;
  int* rowNxt = rowB; int* colNxt = colB;

  int n = 2048;
  for (int i = 0; i < 4; ++i) {
    int N = NB * n, khalf = n >> 1;
    float* statL = stat8 + (size_t)i * 8 * 256;
    // layer io ping-pong: L0 out=A, L1 A->Bb, L2 Bb->A, L3 A->Bb
    const float* Xin  = (i == 2) ? Bb : A;
    float*       Xout = (i == 0 || i == 2) ? A : Bb;
    // CSR payload aliases the INACTIVE edge double-buffer (rowNxt/colNxt):
    // written by csr_build, read through score_k, overwritten by cmp_k at
    // layer end — strictly stream-ordered.
    int*   srow  = rowNxt;
    float* snorm = (float*)colNxt;
    csr_build_k<<<NB, 1024, (size_t)16 * n, stream>>>(
        rowCur, colCur, gcntL + i * NB, dis, off, offe, srow, snorm, n);
    if (i == 0) {
      agg7_k<<<N / 32, 256, 0, stream>>>(x_in, srow, snorm, off, offe, dis, aggx, N);
      conv_fc0_k<<<N / 64, 256, 0, stream>>>(aggx, Wc1, bc, Wf, bf, Xout, N, statL);
    } else {
      conv_fc_k<<<N / 64, 256, 0, stream>>>(
          Xin, bnsc, sel, scale, srow, snorm, off, offe, dis,
          Wc + (size_t)(i - 1) * HB * HB, bc + (size_t)i * HB,
          Wf + (size_t)i * HB * HB, bf + (size_t)i * HB, Xout, N, statL);
    }
    bnfin_k<<<1, 128, 0, stream>>>(statL, bng + (size_t)i * HB, bnb + (size_t)i * HB, bnsc, N);
    score_prep_k<<<N / 4, 256, 0, stream>>>(
        Xout, bnsc, Ws1 + (size_t)i * HB, Ws2 + (size_t)i * HB, selfs, t2v, N);
    score_k<<<(N + 255) / 256, 256, 0, stream>>>(
        selfs, t2v, srow, off, offe, bs + i, score, N);
    int bpg = n / 256;
    rank_topk_k<<<NB * bpg, 256, (size_t)n * 4, stream>>>(
        score, inv, sel, scale, n, khalf, bpg);
    if (i < 3) {
      cmp_k<<<NB * 64, 256, 0, stream>>>(rowCur, colCur, inv, gcntL + i * NB,
                                         rowNxt, colNxt, gcntL + (i + 1) * NB);
      int* t;
      t = rowCur; rowCur = rowNxt; rowNxt = t;
      t = colCur; colCur = colNxt; colNxt = t;
    } else {
      gather_x_k<<<(NB * khalf) / 8, 256, 0, stream>>>(
          Xout, bnsc, sel, scale, Cc, NB * khalf);
    }
    n = khalf;
  }
  pool_k<<<NB, 128, 0, stream>>>(Cc, (float*)d_out, n);
}